// Round 1
// baseline (1772.053 us; speedup 1.0000x reference)
//
#include <hip/hip_runtime.h>

#define NN 16384   // n_nodes
#define DD 64      // feature dim

typedef _Float16 f16x8 __attribute__((ext_vector_type(8)));
typedef short    s16x8 __attribute__((ext_vector_type(8)));
typedef float    f32x4 __attribute__((ext_vector_type(4)));
typedef int      i32x4 __attribute__((ext_vector_type(4)));

// ---------------------------------------------------------------------------
// Pre-pass: convert x (fp32 [NN][64]) into f16, laid out in exact MFMA
// B-fragment order for mfma_f32_16x16x32_f16:
//   ws[((t*4 + c)*64 + l)*8 + j] = x[32*t + (l>>4)*8 + j][c*16 + (l&15)]
// Coalesced version: block t stages its 32x64 fp32 tile through LDS, then
// each thread emits one contiguous f16x8. 512 blocks, one t per block.
// ---------------------------------------------------------------------------
__global__ __launch_bounds__(256) void prep_x(const float* __restrict__ x,
                                              _Float16* __restrict__ ws) {
    __shared__ float sx[32][65];   // +1 pad breaks bank alignment
    const int tid = threadIdx.x;
    const int t   = blockIdx.x;    // 0..511 ; rows 32t .. 32t+31

    // coalesced load: thread reads 32B (8 floats) of one row
    {
        int r  = tid >> 3;          // 0..31
        int c8 = (tid & 7) * 8;     // 0,8,..,56
        const float* src = x + ((size_t)t * 32 + r) * DD + c8;
        f32x4 a = *(const f32x4*)src;
        f32x4 b = *(const f32x4*)(src + 4);
#pragma unroll
        for (int j = 0; j < 4; ++j) { sx[r][c8 + j] = a[j]; sx[r][c8 + 4 + j] = b[j]; }
    }
    __syncthreads();

    const int l = tid & 63;
    const int c = tid >> 6;        // wave id == col-tile
    const int q = l >> 4;
    const int m = l & 15;
    f16x8 v;
#pragma unroll
    for (int j = 0; j < 8; ++j)
        v[j] = (_Float16)sx[q * 8 + j][c * 16 + m];
    // ws f16x8 index: (t*4 + c)*64 + l  ==  t*256 + c*64 + l
    *(f16x8*)(ws + (((size_t)t * 256 + c * 64 + l) * 8)) = v;
}

// ---------------------------------------------------------------------------
// Main GEMM, v2: barrier-free + K-split x4 for occupancy.
//  - grid = 1024 blocks (256 row-blocks x 4 K-quarters) -> 4 blocks/CU,
//    12-16 waves/CU instead of 4.
//  - NO LDS, NO __syncthreads: B-fragments are read directly from the 2 MiB
//    pre-swizzled xs (L2-resident per XCD), so the adj prefetch loads are
//    never drained by a barrier's vmcnt(0).
//  - adj goes global->VGPR nontemporal, chunk double-buffered: 8 dwordx4
//    continuously in flight per wave.
//  - each wave writes a 16x64 f32 partial; reduce_add sums the 4 partials + x.
// ---------------------------------------------------------------------------
__global__ __launch_bounds__(256, 3) void graphpool_gemm(const int* __restrict__ adj,
                                                         const _Float16* __restrict__ xs,
                                                         float* __restrict__ part) {
    const int tid = threadIdx.x;
    const int w   = tid >> 6;
    const int l   = tid & 63;
    const int q   = l >> 4;
    const int m   = l & 15;

    const int rb    = blockIdx.x >> 2;   // row-block 0..255
    const int kq    = blockIdx.x & 3;    // K-quarter 0..3
    const int row16 = rb * 64 + w * 16;
    const int KQ    = NN / 4;            // 4096

    // A: lane l reads adj[row16 + m][kbase + q*8 .. +8)
    const int* aptr = adj + (size_t)(row16 + m) * NN + (size_t)kq * KQ + q * 8;
    // B: f16x8 index for global kstep T, col-tile c: (T*4 + c)*64 + l
    const f16x8* xv = (const f16x8*)xs + (size_t)kq * (KQ / 32) * 256 + l;

    f32x4 acc[4];
#pragma unroll
    for (int c = 0; c < 4; ++c) acc[c] = (f32x4){0.f, 0.f, 0.f, 0.f};

    i32x4 areg[2][4][2];   // [buf][kstep][2x dwordx4] = 8 adj ints per kstep

    auto loadA = [&](int n, int buf) {
#pragma unroll
        for (int s = 0; s < 4; ++s) {
            const i32x4* p = (const i32x4*)(aptr + (size_t)n * 128 + s * 32);
            areg[buf][s][0] = __builtin_nontemporal_load(p);
            areg[buf][s][1] = __builtin_nontemporal_load(p + 1);
        }
    };

    constexpr int NCH = (NN / 4) / 128;  // 32 chunks of K=128
    loadA(0, 0);
    for (int n = 0; n < NCH; ++n) {
        const int buf = n & 1;
        if (n + 1 < NCH) loadA(n + 1, buf ^ 1);   // stays in flight: no barrier
#pragma unroll
        for (int s = 0; s < 4; ++s) {
            int av[8];
            {
                i32x4 v0 = areg[buf][s][0], v1 = areg[buf][s][1];
                av[0] = v0.x; av[1] = v0.y; av[2] = v0.z; av[3] = v0.w;
                av[4] = v1.x; av[5] = v1.y; av[6] = v1.z; av[7] = v1.w;
            }
            s16x8 ai;
#pragma unroll
            for (int j = 0; j < 8; ++j)
                ai[j] = av[j] ? (short)0x3C00 : (short)0;   // 0/1 -> f16 0.0/1.0
            f16x8 af = __builtin_bit_cast(f16x8, ai);
            const f16x8* bp = xv + (size_t)(n * 4 + s) * 256;   // + c*64
#pragma unroll
            for (int c = 0; c < 4; ++c)
                acc[c] = __builtin_amdgcn_mfma_f32_16x16x32_f16(af, bp[c * 64], acc[c], 0, 0, 0);
        }
    }

    // partial C write: col = c*16 + m, row = q*4 + r ; nontemporal (read once)
    float* po = part + (size_t)kq * NN * DD;
#pragma unroll
    for (int c = 0; c < 4; ++c) {
#pragma unroll
        for (int r = 0; r < 4; ++r) {
            size_t off = (size_t)(row16 + q * 4 + r) * DD + c * 16 + m;
            __builtin_nontemporal_store(acc[c][r], po + off);
        }
    }
}

// ---------------------------------------------------------------------------
// Final reduce: out = part[0] + part[1] + part[2] + part[3] + x (self term).
// 20 MiB read + 4 MiB write, ~4 us.
// ---------------------------------------------------------------------------
__global__ __launch_bounds__(256) void reduce_add(const float* __restrict__ part,
                                                  const float* __restrict__ x,
                                                  float* __restrict__ out) {
    size_t i = (size_t)blockIdx.x * 256 + threadIdx.x;   // f32x4 index, 262144 total
    f32x4 v = ((const f32x4*)x)[i];
#pragma unroll
    for (int g = 0; g < 4; ++g)
        v += ((const f32x4*)(part + (size_t)g * NN * DD))[i];
    ((f32x4*)out)[i] = v;
}

// ---------------------------------------------------------------------------
// Safety-net fallback if ws is too small (needs 2 MiB xs + 16 MiB partials).
// ---------------------------------------------------------------------------
__global__ void graphpool_fallback(const int* __restrict__ adj,
                                   const float* __restrict__ x,
                                   float* __restrict__ out) {
    int i = blockIdx.x;
    int d = threadIdx.x;   // 64 threads
    float acc = x[(size_t)i * DD + d];
    const int* row = adj + (size_t)i * NN;
    for (int j = 0; j < NN; ++j)
        if (row[j]) acc += x[(size_t)j * DD + d];
    out[(size_t)i * DD + d] = acc;
}

extern "C" void kernel_launch(void* const* d_in, const int* in_sizes, int n_in,
                              void* d_out, int out_size, void* d_ws, size_t ws_size,
                              hipStream_t stream) {
    const float* x   = (const float*)d_in[0];
    const int*   adj = (const int*)d_in[1];
    float*       out = (float*)d_out;

    const size_t xs_bytes   = (size_t)NN * DD * sizeof(_Float16);   // 2 MiB
    const size_t part_bytes = (size_t)4 * NN * DD * sizeof(float);  // 16 MiB
    if (ws_size >= xs_bytes + part_bytes) {
        _Float16* xs   = (_Float16*)d_ws;
        float*    part = (float*)((char*)d_ws + xs_bytes);
        prep_x<<<512, 256, 0, stream>>>(x, xs);
        graphpool_gemm<<<1024, 256, 0, stream>>>(adj, xs, part);
        reduce_add<<<1024, 256, 0, stream>>>(part, x, out);
    } else {
        graphpool_fallback<<<NN, 64, 0, stream>>>(adj, x, out);
    }
}

// Round 2
// 1695.033 us; speedup vs baseline: 1.0454x; 1.0454x over previous
//
#include <hip/hip_runtime.h>

#define NN 16384   // n_nodes
#define DD 64      // feature dim

typedef _Float16 f16x8 __attribute__((ext_vector_type(8)));
typedef short    s16x8 __attribute__((ext_vector_type(8)));
typedef float    f32x4 __attribute__((ext_vector_type(4)));
typedef int      i32x4 __attribute__((ext_vector_type(4)));

// ---------------------------------------------------------------------------
// Pre-pass: convert x (fp32 [NN][64]) into f16, laid out in exact MFMA
// B-fragment order for mfma_f32_16x16x32_f16:
//   ws[((t*4 + c)*64 + l)*8 + j] = x[32*t + (l>>4)*8 + j][c*16 + (l&15)]
// Coalesced: block t stages its 32x64 fp32 tile through LDS, then each
// thread emits one contiguous f16x8.
// ---------------------------------------------------------------------------
__global__ __launch_bounds__(256) void prep_x(const float* __restrict__ x,
                                              _Float16* __restrict__ ws) {
    __shared__ float sx[32][65];   // +1 pad breaks bank alignment
    const int tid = threadIdx.x;
    const int t   = blockIdx.x;    // 0..511 ; rows 32t .. 32t+31

    {
        int r  = tid >> 3;          // 0..31
        int c8 = (tid & 7) * 8;     // 0,8,..,56
        const float* src = x + ((size_t)t * 32 + r) * DD + c8;
        f32x4 a = *(const f32x4*)src;
        f32x4 b = *(const f32x4*)(src + 4);
#pragma unroll
        for (int j = 0; j < 4; ++j) { sx[r][c8 + j] = a[j]; sx[r][c8 + 4 + j] = b[j]; }
    }
    __syncthreads();

    const int l = tid & 63;
    const int c = tid >> 6;        // wave id == col-tile
    const int q = l >> 4;
    const int m = l & 15;
    f16x8 v;
#pragma unroll
    for (int j = 0; j < 8; ++j)
        v[j] = (_Float16)sx[q * 8 + j][c * 16 + m];
    *(f16x8*)(ws + (((size_t)t * 256 + c * 64 + l) * 8)) = v;
}

// ---------------------------------------------------------------------------
// Main GEMM, v3 = round-0 structure (LDS-staged B keeps the B-dependency on
// lgkmcnt, so the adj vmcnt prefetch queue is never drained inside a chunk)
// + K-split x4 for occupancy (grid 1024 -> ~3 blocks/CU; when one block sits
// in its barrier's vmcnt(0) drain, the other blocks keep the HBM pipe fed).
// Each block: 64 rows x K-quarter (4096). Chunk = 128 K (4 k-steps of 32).
// adj: global->VGPR nontemporal, double-buffered. B: LDS double-buffered.
// Partials to ws; reduce_add sums 4 partials + self term x.
// ---------------------------------------------------------------------------
__global__ __launch_bounds__(256, 3) void graphpool_gemm(const int* __restrict__ adj,
                                                         const _Float16* __restrict__ xs,
                                                         float* __restrict__ part) {
    __shared__ _Float16 sB[2][8192];   // 2 x 16 KiB

    const int tid = threadIdx.x;
    const int w   = tid >> 6;
    const int l   = tid & 63;
    const int q   = l >> 4;
    const int m   = l & 15;

    const int rb    = blockIdx.x >> 2;   // row-block 0..255
    const int kq    = blockIdx.x & 3;    // K-quarter 0..3
    const int row16 = rb * 64 + w * 16;
    constexpr int KQ  = NN / 4;          // 4096
    constexpr int NCH = KQ / 128;        // 32 chunks

    // A: lane l reads adj[row16 + m][kq*KQ + n*128 + s*32 + q*8 .. +8)
    const int* aptr = adj + (size_t)(row16 + m) * NN + (size_t)kq * KQ + q * 8;

    f32x4 acc[4];
#pragma unroll
    for (int c = 0; c < 4; ++c) acc[c] = (f32x4){0.f, 0.f, 0.f, 0.f};

    i32x4 areg[2][4][2];   // [buf][kstep][2x dwordx4] = 8 adj ints per kstep
    f16x8 sreg[4];         // staging regs for next B slab (16 KiB / 256 thr)

    auto loadA = [&](int n, int buf) {
#pragma unroll
        for (int s = 0; s < 4; ++s) {
            const i32x4* p = (const i32x4*)(aptr + (size_t)n * 128 + s * 32);
            areg[buf][s][0] = __builtin_nontemporal_load(p);
            areg[buf][s][1] = __builtin_nontemporal_load(p + 1);
        }
    };
    // chunk n's B slab: f16x8 index kq*32768 + n*1024, identity-copied to LDS
    auto stageRead = [&](int n) {
        const f16x8* src = (const f16x8*)xs + (size_t)kq * 32768 + (size_t)n * 1024;
#pragma unroll
        for (int p = 0; p < 4; ++p) sreg[p] = src[p * 256 + tid];
    };
    auto stageWrite = [&](int buf) {
        f16x8* dst = (f16x8*)sB[buf];
#pragma unroll
        for (int p = 0; p < 4; ++p) dst[p * 256 + tid] = sreg[p];
    };

    // prologue: chunk 0 into buf 0
    stageRead(0);
    loadA(0, 0);
    stageWrite(0);
    __syncthreads();

    for (int n = 0; n < NCH; ++n) {
        const int buf = n & 1;
        const bool pf = (n + 1 < NCH);
        if (pf) { stageRead(n + 1); loadA(n + 1, buf ^ 1); }
#pragma unroll
        for (int s = 0; s < 4; ++s) {
            int av[8];
            {
                i32x4 v0 = areg[buf][s][0], v1 = areg[buf][s][1];
                av[0] = v0.x; av[1] = v0.y; av[2] = v0.z; av[3] = v0.w;
                av[4] = v1.x; av[5] = v1.y; av[6] = v1.z; av[7] = v1.w;
            }
            s16x8 ai;
#pragma unroll
            for (int j = 0; j < 8; ++j)
                ai[j] = av[j] ? (short)0x3C00 : (short)0;   // 0/1 -> f16 0.0/1.0
            f16x8 af = __builtin_bit_cast(f16x8, ai);
#pragma unroll
            for (int c = 0; c < 4; ++c) {
                f16x8 bf = *(const f16x8*)&sB[buf][((s * 4 + c) * 64 + l) * 8];
                acc[c] = __builtin_amdgcn_mfma_f32_16x16x32_f16(af, bf, acc[c], 0, 0, 0);
            }
        }
        if (pf) stageWrite(buf ^ 1);
        __syncthreads();
    }

    // partial C write: col = c*16 + m, row = q*4 + r (plain stores: 16 MiB
    // total, stays L2/L3-resident for the reduce)
    float* po = part + (size_t)kq * NN * DD;
#pragma unroll
    for (int c = 0; c < 4; ++c) {
#pragma unroll
        for (int r = 0; r < 4; ++r) {
            size_t off = (size_t)(row16 + q * 4 + r) * DD + c * 16 + m;
            po[off] = acc[c][r];
        }
    }
}

// ---------------------------------------------------------------------------
// Final reduce: out = part[0..3] + x (self term). ~24 MiB traffic, ~5 us.
// ---------------------------------------------------------------------------
__global__ __launch_bounds__(256) void reduce_add(const float* __restrict__ part,
                                                  const float* __restrict__ x,
                                                  float* __restrict__ out) {
    size_t i = (size_t)blockIdx.x * 256 + threadIdx.x;   // f32x4 index, 262144 total
    f32x4 v = ((const f32x4*)x)[i];
#pragma unroll
    for (int g = 0; g < 4; ++g)
        v += ((const f32x4*)(part + (size_t)g * NN * DD))[i];
    ((f32x4*)out)[i] = v;
}

// ---------------------------------------------------------------------------
// Safety-net fallback if ws is too small (needs 2 MiB xs + 16 MiB partials).
// ---------------------------------------------------------------------------
__global__ void graphpool_fallback(const int* __restrict__ adj,
                                   const float* __restrict__ x,
                                   float* __restrict__ out) {
    int i = blockIdx.x;
    int d = threadIdx.x;   // 64 threads
    float acc = x[(size_t)i * DD + d];
    const int* row = adj + (size_t)i * NN;
    for (int j = 0; j < NN; ++j)
        if (row[j]) acc += x[(size_t)j * DD + d];
    out[(size_t)i * DD + d] = acc;
}

extern "C" void kernel_launch(void* const* d_in, const int* in_sizes, int n_in,
                              void* d_out, int out_size, void* d_ws, size_t ws_size,
                              hipStream_t stream) {
    const float* x   = (const float*)d_in[0];
    const int*   adj = (const int*)d_in[1];
    float*       out = (float*)d_out;

    const size_t xs_bytes   = (size_t)NN * DD * sizeof(_Float16);   // 2 MiB
    const size_t part_bytes = (size_t)4 * NN * DD * sizeof(float);  // 16 MiB
    if (ws_size >= xs_bytes + part_bytes) {
        _Float16* xs   = (_Float16*)d_ws;
        float*    part = (float*)((char*)d_ws + xs_bytes);
        prep_x<<<512, 256, 0, stream>>>(x, xs);
        graphpool_gemm<<<1024, 256, 0, stream>>>(adj, xs, part);
        reduce_add<<<1024, 256, 0, stream>>>(part, x, out);
    } else {
        graphpool_fallback<<<NN, 64, 0, stream>>>(adj, x, out);
    }
}

// Round 3
// 1681.402 us; speedup vs baseline: 1.0539x; 1.0081x over previous
//
#include <hip/hip_runtime.h>

#define NN 16384   // n_nodes
#define DD 64      // feature dim

typedef _Float16 f16x8 __attribute__((ext_vector_type(8)));
typedef short    s16x8 __attribute__((ext_vector_type(8)));
typedef float    f32x4 __attribute__((ext_vector_type(4)));
typedef int      i32x4 __attribute__((ext_vector_type(4)));
typedef unsigned u32;

// ---------------------------------------------------------------------------
// prep_adj: bit-pack adj (int32 0/1, 1 GiB) -> pk (32 MiB).
// Output dword g holds bit i = (adj[g*32 + i] != 0).  Rows are 512 dwords
// (16384/32), so row r owns dwords [r*512, (r+1)*512).
// Streaming, barrier-free: lane reads 32 ints (8x dwordx4, nontemporal),
// builds one dword, stores it; consecutive lanes -> consecutive out dwords.
// 2048 blocks x 256 thr x 16 iters covers all 8388608 output dwords.
// Expected ~200 us (1 GiB read at ~5.5-6 TB/s).
// ---------------------------------------------------------------------------
__global__ __launch_bounds__(256) void prep_adj(const int* __restrict__ adj,
                                                u32* __restrict__ pk) {
    const u32 tid = blockIdx.x * 256 + threadIdx.x;   // 524288 threads
    for (int it = 0; it < 16; ++it) {
        size_t g = (size_t)it * (2048 * 256) + tid;
        const i32x4* src = (const i32x4*)(adj + g * 32);
        u32 b = 0;
#pragma unroll
        for (int j = 0; j < 8; ++j) {
            i32x4 v = __builtin_nontemporal_load(src + j);
            b |= (u32)(v.x != 0) << (j * 4 + 0);
            b |= (u32)(v.y != 0) << (j * 4 + 1);
            b |= (u32)(v.z != 0) << (j * 4 + 2);
            b |= (u32)(v.w != 0) << (j * 4 + 3);
        }
        pk[g] = b;
    }
}

// ---------------------------------------------------------------------------
// prep_x: convert x (fp32 [NN][64]) into f16 in exact MFMA B-fragment order:
//   xs[((t*4 + c)*64 + l)*8 + j] = x[32*t + (l>>4)*8 + j][c*16 + (l&15)]
// Coalesced via an LDS transpose of each 32x64 tile.
// ---------------------------------------------------------------------------
__global__ __launch_bounds__(256) void prep_x(const float* __restrict__ x,
                                              _Float16* __restrict__ ws) {
    __shared__ float sx[32][65];
    const int tid = threadIdx.x;
    const int t   = blockIdx.x;    // 0..511 ; rows 32t .. 32t+31
    {
        int r  = tid >> 3;
        int c8 = (tid & 7) * 8;
        const float* src = x + ((size_t)t * 32 + r) * DD + c8;
        f32x4 a = *(const f32x4*)src;
        f32x4 b = *(const f32x4*)(src + 4);
#pragma unroll
        for (int j = 0; j < 4; ++j) { sx[r][c8 + j] = a[j]; sx[r][c8 + 4 + j] = b[j]; }
    }
    __syncthreads();
    const int l = tid & 63;
    const int c = tid >> 6;
    const int q = l >> 4;
    const int m = l & 15;
    f16x8 v;
#pragma unroll
    for (int j = 0; j < 8; ++j)
        v[j] = (_Float16)sx[q * 8 + j][c * 16 + m];
    *(f16x8*)(ws + (((size_t)t * 256 + c * 64 + l) * 8)) = v;
}

// ---------------------------------------------------------------------------
// Main GEMM on bit-packed adj. R0's proven structure (LDS-staged B on lgkmcnt,
// adj bits on vmcnt, one barrier per K=128 chunk), but A is now 16 B/lane/chunk
// of bits instead of 512 B/lane of int32 -- the barrier drain waits on a few
// hundred cycles of L2/L3 latency, not 48 KiB of HBM.
// A-frag: chunk n, kstep s, lane (q=l>>4, m=l&15):
//   af[j] = bit (8q+j) of dword s of pk_i32x4[(row16+m)*128 + n]
//         = adj[row16+m][128n + 32s + 8q + j]   (verified mapping)
// Epilogue writes out = acc + x directly (no partials).
// ---------------------------------------------------------------------------
__global__ __launch_bounds__(256) void graphpool_gemm(const u32* __restrict__ pk,
                                                      const float* __restrict__ x,
                                                      const _Float16* __restrict__ xs,
                                                      float* __restrict__ out) {
    __shared__ _Float16 sB[2][8192];   // 2 x 16 KiB (K=128 x 64 cols f16)

    const int tid = threadIdx.x;
    const int w   = tid >> 6;
    const int l   = tid & 63;
    const int q   = l >> 4;
    const int m   = l & 15;
    const int row16 = blockIdx.x * 64 + w * 16;

    // A bits: i32x4 index row*128 + n  (row stride = 512 dwords)
    const i32x4* aptr = (const i32x4*)pk + (size_t)(row16 + m) * 128;

    f32x4 acc[4];
#pragma unroll
    for (int c = 0; c < 4; ++c) acc[c] = (f32x4){0.f, 0.f, 0.f, 0.f};

    i32x4 areg[2];     // [buf] : 16 B of bits = whole K=128 chunk for this lane
    f16x8 sreg[4];     // staging regs for next B slab (16 KiB / 256 thr)

    auto loadA = [&](int n, int buf) { areg[buf] = aptr[n]; };
    auto stageRead = [&](int n) {
        const f16x8* src = (const f16x8*)xs + (size_t)n * 1024;
#pragma unroll
        for (int p = 0; p < 4; ++p) sreg[p] = src[p * 256 + tid];
    };
    auto stageWrite = [&](int buf) {
        f16x8* dst = (f16x8*)sB[buf];
#pragma unroll
        for (int p = 0; p < 4; ++p) dst[p * 256 + tid] = sreg[p];
    };

    // prologue
    stageRead(0);
    loadA(0, 0);
    stageWrite(0);
    __syncthreads();

    constexpr int NCH = NN / 128;   // 128 chunks
    for (int n = 0; n < NCH; ++n) {
        const int buf = n & 1;
        const bool pf = (n + 1 < NCH);
        if (pf) { stageRead(n + 1); loadA(n + 1, buf ^ 1); }
#pragma unroll
        for (int s = 0; s < 4; ++s) {
            u32 byte = (((u32)areg[buf][s]) >> (q * 8)) & 0xffu;
            s16x8 ai;
#pragma unroll
            for (int j = 0; j < 8; ++j)
                ai[j] = ((byte >> j) & 1u) ? (short)0x3C00 : (short)0;
            f16x8 af = __builtin_bit_cast(f16x8, ai);
#pragma unroll
            for (int c = 0; c < 4; ++c) {
                f16x8 bf = *(const f16x8*)&sB[buf][((s * 4 + c) * 64 + l) * 8];
                acc[c] = __builtin_amdgcn_mfma_f32_16x16x32_f16(af, bf, acc[c], 0, 0, 0);
            }
        }
        if (pf) stageWrite(buf ^ 1);
        __syncthreads();
    }

    // epilogue: C layout col = c*16+m, row = q*4+r ; add self term +x
#pragma unroll
    for (int c = 0; c < 4; ++c) {
#pragma unroll
        for (int r = 0; r < 4; ++r) {
            int row = row16 + q * 4 + r;
            int col = c * 16 + m;
            size_t off = (size_t)row * DD + col;
            out[off] = acc[c][r] + x[off];
        }
    }
}

// ---------------------------------------------------------------------------
// Safety-net fallback if ws is too small (needs 2 MiB xs + 32 MiB pk).
// ---------------------------------------------------------------------------
__global__ void graphpool_fallback(const int* __restrict__ adj,
                                   const float* __restrict__ x,
                                   float* __restrict__ out) {
    int i = blockIdx.x;
    int d = threadIdx.x;   // 64 threads
    float acc = x[(size_t)i * DD + d];
    const int* row = adj + (size_t)i * NN;
    for (int j = 0; j < NN; ++j)
        if (row[j]) acc += x[(size_t)j * DD + d];
    out[(size_t)i * DD + d] = acc;
}

extern "C" void kernel_launch(void* const* d_in, const int* in_sizes, int n_in,
                              void* d_out, int out_size, void* d_ws, size_t ws_size,
                              hipStream_t stream) {
    const float* x   = (const float*)d_in[0];
    const int*   adj = (const int*)d_in[1];
    float*       out = (float*)d_out;

    const size_t xs_bytes = (size_t)NN * DD * sizeof(_Float16);      // 2 MiB
    const size_t pk_bytes = (size_t)NN * (NN / 32) * sizeof(u32);    // 32 MiB
    if (ws_size >= xs_bytes + pk_bytes) {
        _Float16* xs = (_Float16*)d_ws;
        u32*      pk = (u32*)((char*)d_ws + xs_bytes);
        prep_adj<<<2048, 256, 0, stream>>>(adj, pk);
        prep_x<<<512, 256, 0, stream>>>(x, xs);
        graphpool_gemm<<<256, 256, 0, stream>>>(pk, x, xs, out);
    } else {
        graphpool_fallback<<<NN, 64, 0, stream>>>(adj, x, out);
    }
}

// Round 4
// 1388.016 us; speedup vs baseline: 1.2767x; 1.2114x over previous
//
#include <hip/hip_runtime.h>

#define NN 16384   // n_nodes
#define DD 64      // feature dim

typedef _Float16 f16x8 __attribute__((ext_vector_type(8)));
typedef short    s16x8 __attribute__((ext_vector_type(8)));
typedef float    f32x4 __attribute__((ext_vector_type(4)));
typedef int      i32x4 __attribute__((ext_vector_type(4)));
typedef int      i32x2 __attribute__((ext_vector_type(2)));
typedef unsigned u32;
typedef unsigned long long u64;

// ---------------------------------------------------------------------------
// prep_x: convert x (fp32 [NN][64]) into f16 in exact MFMA B-fragment order:
//   xs[((t*4 + c)*64 + l)*8 + j] = x[32*t + (l>>4)*8 + j][c*16 + (l&15)]
// Coalesced via an LDS transpose of each 32x64 tile.  (proven in R2/R3)
// ---------------------------------------------------------------------------
__global__ __launch_bounds__(256) void prep_x(const float* __restrict__ x,
                                              _Float16* __restrict__ ws) {
    __shared__ float sx[32][65];
    const int tid = threadIdx.x;
    const int t   = blockIdx.x;    // 0..511 ; rows 32t .. 32t+31
    {
        int r  = tid >> 3;
        int c8 = (tid & 7) * 8;
        const float* src = x + ((size_t)t * 32 + r) * DD + c8;
        f32x4 a = *(const f32x4*)src;
        f32x4 b = *(const f32x4*)(src + 4);
#pragma unroll
        for (int j = 0; j < 4; ++j) { sx[r][c8 + j] = a[j]; sx[r][c8 + 4 + j] = b[j]; }
    }
    __syncthreads();
    const int l = tid & 63;
    const int c = tid >> 6;
    const int q = l >> 4;
    const int m = l & 15;
    f16x8 v;
#pragma unroll
    for (int j = 0; j < 8; ++j)
        v[j] = (_Float16)sx[q * 8 + j][c * 16 + m];
    *(f16x8*)(ws + (((size_t)t * 256 + c * 64 + l) * 8)) = v;
}

// ---------------------------------------------------------------------------
// Fused GEMM: adj is read ONCE, fully coalesced, and bit-packed in-flight
// with __ballot.  Per chunk (K=128) each wave:
//   - loads its 16 rows as i32x2/lane (512 B contiguous per instruction),
//   - 2 ballots/row -> 4 dwords of bits -> LDS A-buffer (64 rows x 4 dw),
//   - MFMA side: 1 ds_read_b128/lane of row bits + bit-extract -> f16 A-frag.
// Bit mapping (verified): k_local = 32s+8q+j ->
//   dword (j&1)*2 + (s>>1), bit 16*(s&1) + 4q + (j>>1).
// B: LDS double-buffered from pre-swizzled xs (L2-resident) as before.
// K-split x2: 512 blocks -> 2 blocks/CU (LDS 68 KiB), 8 waves/CU, so one
// block's barrier drain is covered by the other block's stream.
// ---------------------------------------------------------------------------
__global__ __launch_bounds__(256, 3) void graphpool_gemm(const int* __restrict__ adj,
                                                         const _Float16* __restrict__ xs,
                                                         float* __restrict__ part) {
    __shared__ _Float16 sB[2][8192];   // 2 x 16 KiB
    __shared__ u32      sA[2][256];    // 2 x (64 rows x 4 dwords)

    const int tid = threadIdx.x;
    const int w   = tid >> 6;
    const int l   = tid & 63;
    const int q   = l >> 4;
    const int m   = l & 15;

    const int rb    = blockIdx.x >> 1;   // row-block 0..255
    const int kq    = blockIdx.x & 1;    // K-half 0..1
    const int row16 = rb * 64 + w * 16;
    constexpr int KH  = NN / 2;          // 8192
    constexpr int NCH = KH / 128;        // 64 chunks

    // wave w packs (and consumes) rows row16..row16+15, k-base kq*KH
    const int* abase = adj + (size_t)row16 * NN + (size_t)kq * KH;

    f32x4 acc[4];
#pragma unroll
    for (int c = 0; c < 4; ++c) acc[c] = (f32x4){0.f, 0.f, 0.f, 0.f};

    i32x2 areg[16];    // 16 rows x (2 ints per lane) for the next chunk
    f16x8 sreg[4];     // B staging regs

    auto loadAdj = [&](int n) {
#pragma unroll
        for (int rr = 0; rr < 16; ++rr) {
            const i32x2* p = (const i32x2*)(abase + (size_t)rr * NN + n * 128);
            areg[rr] = p[l];            // lane l: ints 2l, 2l+1 (coalesced 512 B)
        }
    };
    auto packA = [&](int buf) {
        u32 mine = 0;
#pragma unroll
        for (int rr = 0; rr < 16; ++rr) {
            u64 b0 = __ballot(areg[rr].x != 0);   // bit i <-> k_local = 2i
            u64 b1 = __ballot(areg[rr].y != 0);   // bit i <-> k_local = 2i+1
            u32 lo0 = (u32)b0, hi0 = (u32)(b0 >> 32);
            u32 lo1 = (u32)b1, hi1 = (u32)(b1 >> 32);
            u32 sa  = (l & 1) ? hi0 : lo0;        // half   = l&1
            u32 sb  = (l & 1) ? hi1 : lo1;
            u32 sel = (l & 2) ? sb : sa;          // parity = (l>>1)&1
            if ((l >> 2) == rr) mine = sel;       // lane l owns row l>>2, dword l&3
        }
        sA[buf][w * 64 + l] = mine;               // coalesced, conflict-free
    };
    auto stageRead = [&](int n) {   // global chunk index g = kq*NCH + n
        const f16x8* src = (const f16x8*)xs + ((size_t)kq * NCH + n) * 1024;
#pragma unroll
        for (int p = 0; p < 4; ++p) sreg[p] = src[p * 256 + tid];
    };
    auto stageWrite = [&](int buf) {
        f16x8* dst = (f16x8*)sB[buf];
#pragma unroll
        for (int p = 0; p < 4; ++p) dst[p * 256 + tid] = sreg[p];
    };

    // prologue: chunk 0 into buf 0
    loadAdj(0);
    stageRead(0);
    packA(0);
    stageWrite(0);
    __syncthreads();

    for (int n = 0; n < NCH; ++n) {
        const int buf = n & 1;
        const bool pf = (n + 1 < NCH);
        if (pf) { loadAdj(n + 1); stageRead(n + 1); }   // HBM + L2 loads in flight

        i32x4 rowAi = *(const i32x4*)&sA[buf][(w * 16 + m) * 4];
#pragma unroll
        for (int s = 0; s < 4; ++s) {
            const u32 bq = 16 * (s & 1) + 4 * q;
            const u32 dE = (u32)rowAi[s >> 1];        // parity 0 dword
            const u32 dO = (u32)rowAi[2 + (s >> 1)];  // parity 1 dword
            s16x8 ai;
#pragma unroll
            for (int j = 0; j < 8; ++j) {
                u32 d = (j & 1) ? dO : dE;
                ai[j] = ((d >> (bq + (j >> 1))) & 1u) ? (short)0x3C00 : (short)0;
            }
            f16x8 af = __builtin_bit_cast(f16x8, ai);
#pragma unroll
            for (int c = 0; c < 4; ++c) {
                f16x8 bf = *(const f16x8*)&sB[buf][((s * 4 + c) * 64 + l) * 8];
                acc[c] = __builtin_amdgcn_mfma_f32_16x16x32_f16(af, bf, acc[c], 0, 0, 0);
            }
        }

        if (pf) { packA(buf ^ 1); stageWrite(buf ^ 1); }
        __syncthreads();
    }

    // partial C write: col = c*16+m, row = q*4+r
    float* po = part + (size_t)kq * NN * DD;
#pragma unroll
    for (int c = 0; c < 4; ++c) {
#pragma unroll
        for (int r = 0; r < 4; ++r) {
            size_t off = (size_t)(row16 + q * 4 + r) * DD + c * 16 + m;
            po[off] = acc[c][r];
        }
    }
}

// ---------------------------------------------------------------------------
// Final reduce: out = part[0] + part[1] + x (self term). ~16 MiB, ~3 us.
// ---------------------------------------------------------------------------
__global__ __launch_bounds__(256) void reduce_add(const float* __restrict__ part,
                                                  const float* __restrict__ x,
                                                  float* __restrict__ out) {
    size_t i = (size_t)blockIdx.x * 256 + threadIdx.x;   // f32x4 index, 262144 total
    f32x4 v = ((const f32x4*)x)[i];
    v += ((const f32x4*)part)[i];
    v += ((const f32x4*)(part + (size_t)NN * DD))[i];
    ((f32x4*)out)[i] = v;
}

// ---------------------------------------------------------------------------
// Safety-net fallback if ws is too small (needs 2 MiB xs + 8 MiB partials).
// ---------------------------------------------------------------------------
__global__ void graphpool_fallback(const int* __restrict__ adj,
                                   const float* __restrict__ x,
                                   float* __restrict__ out) {
    int i = blockIdx.x;
    int d = threadIdx.x;   // 64 threads
    float acc = x[(size_t)i * DD + d];
    const int* row = adj + (size_t)i * NN;
    for (int j = 0; j < NN; ++j)
        if (row[j]) acc += x[(size_t)j * DD + d];
    out[(size_t)i * DD + d] = acc;
}

extern "C" void kernel_launch(void* const* d_in, const int* in_sizes, int n_in,
                              void* d_out, int out_size, void* d_ws, size_t ws_size,
                              hipStream_t stream) {
    const float* x   = (const float*)d_in[0];
    const int*   adj = (const int*)d_in[1];
    float*       out = (float*)d_out;

    const size_t xs_bytes   = (size_t)NN * DD * sizeof(_Float16);   // 2 MiB
    const size_t part_bytes = (size_t)2 * NN * DD * sizeof(float);  // 8 MiB
    if (ws_size >= xs_bytes + part_bytes) {
        _Float16* xs   = (_Float16*)d_ws;
        float*    part = (float*)((char*)d_ws + xs_bytes);
        prep_x<<<512, 256, 0, stream>>>(x, xs);
        graphpool_gemm<<<512, 256, 0, stream>>>(adj, xs, part);
        reduce_add<<<1024, 256, 0, stream>>>(part, x, out);
    } else {
        graphpool_fallback<<<NN, 64, 0, stream>>>(adj, x, out);
    }
}

// Round 6
// 1362.870 us; speedup vs baseline: 1.3002x; 1.0185x over previous
//
#include <hip/hip_runtime.h>

#define NN 16384   // n_nodes
#define DD 64      // feature dim
#define SPLIT 32            // K-splits per row-block
#define KQ (NN / SPLIT)     // 512 K per block
#define NCH (KQ / 128)      // 4 chunks of K=128 per block

typedef _Float16 f16x8 __attribute__((ext_vector_type(8)));
typedef short    s16x8 __attribute__((ext_vector_type(8)));
typedef float    f32x4 __attribute__((ext_vector_type(4)));
typedef int      i32x4 __attribute__((ext_vector_type(4)));
typedef int      i32x2 __attribute__((ext_vector_type(2)));
typedef unsigned u32;
typedef unsigned long long u64;

// ---------------------------------------------------------------------------
// prep_x: convert x (fp32 [NN][64]) into f16 in exact MFMA B-fragment order:
//   xs[((t*4 + c)*64 + l)*8 + j] = x[32*t + (l>>4)*8 + j][c*16 + (l&15)]
// Coalesced via an LDS transpose of each 32x64 tile.  (proven R2-R4)
// ---------------------------------------------------------------------------
__global__ __launch_bounds__(256) void prep_x(const float* __restrict__ x,
                                              _Float16* __restrict__ ws) {
    __shared__ float sx[32][65];
    const int tid = threadIdx.x;
    const int t   = blockIdx.x;    // 0..511 ; rows 32t .. 32t+31
    {
        int r  = tid >> 3;
        int c8 = (tid & 7) * 8;
        const float* src = x + ((size_t)t * 32 + r) * DD + c8;
        f32x4 a = *(const f32x4*)src;
        f32x4 b = *(const f32x4*)(src + 4);
#pragma unroll
        for (int j = 0; j < 4; ++j) { sx[r][c8 + j] = a[j]; sx[r][c8 + 4 + j] = b[j]; }
    }
    __syncthreads();
    const int l = tid & 63;
    const int c = tid >> 6;
    const int q = l >> 4;
    const int m = l & 15;
    f16x8 v;
#pragma unroll
    for (int j = 0; j < 8; ++j)
        v[j] = (_Float16)sx[q * 8 + j][c * 16 + m];
    *(f16x8*)(ws + (((size_t)t * 256 + c * 64 + l) * 8)) = v;
}

// ---------------------------------------------------------------------------
// Zero-barrier-stream GEMM.  Block (rb,kq): rows rb*64..+63, K range
// [kq*512, +512).  The whole B panel (4 slabs = 64 KiB) is staged into LDS
// up front behind ONE barrier; after that the K-loop has NO barriers, so the
// compiler emits only counted s_waitcnt vmcnt(N) for the coalesced adj row
// loads -- the prefetch queue is never drained (R1/R4 lesson).
// A-side: ballot bit-pack (proven R4 mapping) + ds_bpermute wave-local
// exchange instead of the LDS round-trip:
//   lane (m*4+d) holds dword d of row m  ->  rowAi[d] = bpermute(m*4+d).
// 2 blocks/CU (64 KiB LDS), 8 waves/CU; ~32 adj loads in flight per wave.
// ---------------------------------------------------------------------------
__global__ __launch_bounds__(256, 2) void graphpool_gemm(const int* __restrict__ adj,
                                                         const _Float16* __restrict__ xs,
                                                         float* __restrict__ part) {
    __shared__ _Float16 sB[NCH][8192];   // 4 x 16 KiB = 64 KiB

    const int tid = threadIdx.x;
    const int w   = tid >> 6;
    const int l   = tid & 63;
    const int q   = l >> 4;
    const int m   = l & 15;

    const int rb    = blockIdx.x >> 5;   // row-block 0..255
    const int kq    = blockIdx.x & 31;   // K-split  0..31
    const int row16 = rb * 64 + w * 16;

    // stage entire B panel (L2-resident xs), then the ONLY barrier
#pragma unroll
    for (int n = 0; n < NCH; ++n) {
        const f16x8* src = (const f16x8*)xs + ((size_t)(kq * NCH + n)) * 1024;
        f16x8 t0 = src[tid], t1 = src[256 + tid], t2 = src[512 + tid], t3 = src[768 + tid];
        f16x8* dst = (f16x8*)sB[n];
        dst[tid] = t0; dst[256 + tid] = t1; dst[512 + tid] = t2; dst[768 + tid] = t3;
    }
    __syncthreads();

    // adj loads all issued AFTER the barrier: never drained again
    const int* abase = adj + (size_t)row16 * NN + (size_t)kq * KQ;

    f32x4 acc[4];
#pragma unroll
    for (int c = 0; c < 4; ++c) acc[c] = (f32x4){0.f, 0.f, 0.f, 0.f};

    i32x2 areg[2][16];   // 2-chunk rolling window; [buf][row]

    auto loadAdj = [&](int n, int buf) {
#pragma unroll
        for (int rr = 0; rr < 16; ++rr)
            areg[buf][rr] = ((const i32x2*)(abase + (size_t)rr * NN + n * 128))[l];
    };

    loadAdj(0, 0);
    loadAdj(1, 1);

#pragma unroll
    for (int n = 0; n < NCH; ++n) {
        const int buf = n & 1;

        // ballot-pack chunk n: lane (rr*4+d) ends with dword d of row rr
        // (dword d = half (d&1) of ballot parity (d>>1); bit i of b_p is
        //  k_local = 2i + p -- proven R4 mapping)
        u32 mine = 0;
#pragma unroll
        for (int rr = 0; rr < 16; ++rr) {
            u64 b0 = __ballot(areg[buf][rr].x != 0);
            u64 b1 = __ballot(areg[buf][rr].y != 0);
            u32 sa = (l & 1) ? (u32)(b0 >> 32) : (u32)b0;
            u32 sb = (l & 1) ? (u32)(b1 >> 32) : (u32)b1;
            u32 sel = (l & 2) ? sb : sa;
            if ((l >> 2) == rr) mine = sel;
        }

        if (n + 2 < NCH) loadAdj(n + 2, buf);   // refill window (regs consumed)

        // wave-local exchange: rowAi[d] = dword d of row m (no barrier)
        i32x4 rowAi;
#pragma unroll
        for (int d = 0; d < 4; ++d)
            rowAi[d] = __builtin_amdgcn_ds_bpermute(((m << 2) | d) << 2, (int)mine);

#pragma unroll
        for (int s = 0; s < 4; ++s) {
            const u32 bq = 16 * (s & 1) + 4 * q;
            const u32 dE = (u32)rowAi[s >> 1];        // parity-0 dword
            const u32 dO = (u32)rowAi[2 + (s >> 1)];  // parity-1 dword
            s16x8 ai;
#pragma unroll
            for (int j = 0; j < 8; ++j) {
                u32 dd = (j & 1) ? dO : dE;
                ai[j] = ((dd >> (bq + (j >> 1))) & 1u) ? (short)0x3C00 : (short)0;
            }
            f16x8 af = __builtin_bit_cast(f16x8, ai);
#pragma unroll
            for (int c = 0; c < 4; ++c) {
                f16x8 bf = *(const f16x8*)&sB[n][((s * 4 + c) * 64 + l) * 8];
                acc[c] = __builtin_amdgcn_mfma_f32_16x16x32_f16(af, bf, acc[c], 0, 0, 0);
            }
        }
    }

    // partial C write: col = c*16+m, row = q*4+r  (128 MiB total -> L3)
    float* po = part + (size_t)kq * NN * DD;
#pragma unroll
    for (int c = 0; c < 4; ++c) {
#pragma unroll
        for (int r = 0; r < 4; ++r) {
            size_t off = (size_t)(row16 + q * 4 + r) * DD + c * 16 + m;
            po[off] = acc[c][r];
        }
    }
}

// ---------------------------------------------------------------------------
// Final reduce: out = sum(part[0..31]) + x (self term).  ~132 MiB, L3-hot.
// ---------------------------------------------------------------------------
__global__ __launch_bounds__(256) void reduce_add(const float* __restrict__ part,
                                                  const float* __restrict__ x,
                                                  float* __restrict__ out) {
    size_t i = (size_t)blockIdx.x * 256 + threadIdx.x;   // f32x4 index, 262144 total
    f32x4 v = ((const f32x4*)x)[i];
#pragma unroll
    for (int g = 0; g < SPLIT; ++g)
        v += ((const f32x4*)(part + (size_t)g * NN * DD))[i];
    ((f32x4*)out)[i] = v;
}

// ---------------------------------------------------------------------------
// Safety-net fallback if ws is too small (needs 2 MiB xs + 128 MiB partials).
// ---------------------------------------------------------------------------
__global__ void graphpool_fallback(const int* __restrict__ adj,
                                   const float* __restrict__ x,
                                   float* __restrict__ out) {
    int i = blockIdx.x;
    int d = threadIdx.x;   // 64 threads
    float acc = x[(size_t)i * DD + d];
    const int* row = adj + (size_t)i * NN;
    for (int j = 0; j < NN; ++j)
        if (row[j]) acc += x[(size_t)j * DD + d];
    out[(size_t)i * DD + d] = acc;
}

extern "C" void kernel_launch(void* const* d_in, const int* in_sizes, int n_in,
                              void* d_out, int out_size, void* d_ws, size_t ws_size,
                              hipStream_t stream) {
    const float* x   = (const float*)d_in[0];
    const int*   adj = (const int*)d_in[1];
    float*       out = (float*)d_out;

    const size_t xs_bytes   = (size_t)NN * DD * sizeof(_Float16);        // 2 MiB
    const size_t part_bytes = (size_t)SPLIT * NN * DD * sizeof(float);   // 128 MiB
    if (ws_size >= xs_bytes + part_bytes) {
        _Float16* xs   = (_Float16*)d_ws;
        float*    part = (float*)((char*)d_ws + xs_bytes);
        prep_x<<<512, 256, 0, stream>>>(x, xs);
        graphpool_gemm<<<256 * SPLIT, 256, 0, stream>>>(adj, xs, part);
        reduce_add<<<1024, 256, 0, stream>>>(part, x, out);
    } else {
        graphpool_fallback<<<NN, 64, 0, stream>>>(adj, x, out);
    }
}